// Round 1
// baseline (747.797 us; speedup 1.0000x reference)
//
#include <hip/hip_runtime.h>
#include <math.h>

#define T_TOTAL 16384
#define DMODEL  1024
#define MARGIN  2.5e-3f

typedef __attribute__((ext_vector_type(8))) _Float16 f16x8;
typedef __attribute__((ext_vector_type(4))) float    f32x4;

#define SEL3(l, a, b, c) ((l) == 0 ? (a) : (l) == 1 ? (b) : (c))

__device__ __forceinline__ float gelu_exact(float x) {
    return 0.5f * x * (1.0f + erff(x * 0.7071067811865476f));
}
__device__ __forceinline__ unsigned short f2h(float f) {
    union { _Float16 h; unsigned short s; } c; c.h = (_Float16)f; return c.s;
}
__device__ __forceinline__ float h2f(unsigned short u) {
    union { unsigned short s; _Float16 h; } c; c.s = u; return (float)c.h;
}
// async global->LDS, 16B per lane; LDS dest = wave-uniform base + lane*16.
__device__ __forceinline__ void gll16(const void* g, void* l) {
    __builtin_amdgcn_global_load_lds(
        (const __attribute__((address_space(1))) unsigned int*)g,
        (__attribute__((address_space(3))) unsigned int*)l, 16, 0, 0);
}

// Panel-chunked XCD swizzle (bijective when gridDim.x % 64 == 0).
// Groups of 8 consecutive WORK ids (one shared A-panel) land on the same XCD
// in consecutive slots; each XCD walks the work range in order (so with
// longest-level-first work ordering every XCD starts on the long blocks).
__device__ __forceinline__ int swz_bid() {
    const int b = blockIdx.x;
    const int G = gridDim.x;
    if (G & 63) return b;
    const int x = b & 7, j = b >> 3;
    return (x + 8 * (j >> 3)) * 8 + (j & 7);
}

// ---------------------------------------------------------------------------
// k_cvt: Xh = f16(X), whole tensor. 8 floats/thread.
// ---------------------------------------------------------------------------
__global__ __launch_bounds__(256) void k_cvt(
    const float* __restrict__ X, unsigned short* __restrict__ Xh)
{
    const size_t i = ((size_t)blockIdx.x * 256 + threadIdx.x) * 8;
    float4 f0 = *(const float4*)(X + i);
    float4 f1 = *(const float4*)(X + i + 4);
    unsigned short o[8] __attribute__((aligned(16)));
    o[0]=f2h(f0.x); o[1]=f2h(f0.y); o[2]=f2h(f0.z); o[3]=f2h(f0.w);
    o[4]=f2h(f1.x); o[5]=f2h(f1.y); o[6]=f2h(f1.z); o[7]=f2h(f1.w);
    *(uint4*)(Xh + i) = *(uint4*)o;
}

// ---------------------------------------------------------------------------
// k_pack_all: pack all 7 fp32 weights [K][N] into f16 tiles
// [N/128][K/32][128][32] in ONE launch. tile[r][c] = W[kt*32+c][nt*128+r].
// ---------------------------------------------------------------------------
struct PackP {
    const float* src[7];
    unsigned short* dst[7];
    int K[7], N[7];
    int boff[8];
};

__global__ __launch_bounds__(256) void k_pack_all(PackP p)
{
    const int gb = blockIdx.x;
    int t = 0;
    while (t < 6 && gb >= p.boff[t + 1]) ++t;
    const int lb = gb - p.boff[t];
    const float* src = p.src[t];
    unsigned short* dst = p.dst[t];
    const int K = p.K[t], N = p.N[t];

    const int ktiles = K >> 5;
    const int nt = lb / ktiles;
    const int kt = lb % ktiles;
    __shared__ float ls[32][129];
    const int tid = threadIdx.x;
    {
        const int c  = tid >> 3;
        const int n0 = (tid & 7) * 16;
        const float* s = src + (size_t)(kt * 32 + c) * N + (size_t)nt * 128 + n0;
#pragma unroll
        for (int v = 0; v < 4; ++v) {
            float4 f = *(const float4*)(s + v * 4);
            ls[c][n0 + v*4 + 0] = f.x; ls[c][n0 + v*4 + 1] = f.y;
            ls[c][n0 + v*4 + 2] = f.z; ls[c][n0 + v*4 + 3] = f.w;
        }
    }
    __syncthreads();
    {
        const int r  = tid >> 1;
        const int c0 = (tid & 1) * 16;
        unsigned short tmp[16] __attribute__((aligned(16)));
#pragma unroll
        for (int c = 0; c < 16; ++c) tmp[c] = f2h(ls[c0 + c][r]);
        unsigned short* d = dst + (size_t)lb * (128 * 32) + r * 32 + c0;
        *(uint4*)(d)     = *(uint4*)&tmp[0];
        *(uint4*)(d + 8) = *(uint4*)&tmp[8];
    }
}

// ---------------------------------------------------------------------------
// k_h: H = f16( GELU(Xh @ Wc1 + bc1) ), m97-style. [16384x1024]@[1024x512].
// ---------------------------------------------------------------------------
__global__ __launch_bounds__(256) void k_h(
    const unsigned short* __restrict__ Xh, const unsigned short* __restrict__ Wq,
    const float* __restrict__ bc1, unsigned short* __restrict__ H)
{
    const int bid = swz_bid();
    const int mt = bid >> 2;
    const int nt = bid & 3;
    __shared__ __align__(16) unsigned short As[128 * 32];
    __shared__ __align__(16) unsigned short Bs[128 * 32];

    const int tid = threadIdx.x;
    const int w = tid >> 6, ln = tid & 63;
    const int wr = w >> 1, wc = w & 1;
    const int q = ln >> 4, tq = ln & 15;

    f32x4 acc[4][4];
#pragma unroll
    for (int i = 0; i < 4; ++i)
#pragma unroll
        for (int j = 0; j < 4; ++j) acc[i][j] = (f32x4){0.f, 0.f, 0.f, 0.f};

    const int r0 = mt * 128 + w * 32 + (ln >> 2);
    const unsigned short* a0 = Xh + (size_t)r0 * DMODEL + (ln & 3) * 8;
    const unsigned short* a1 = a0 + (size_t)16 * DMODEL;
    const unsigned short* bsr = Wq + (size_t)nt * 32 * 4096 + w * 1024 + ln * 8;
    unsigned short* lA = As + w * 1024;
    unsigned short* lB = Bs + w * 1024;

    for (int kt = 0; kt < 32; ++kt) {
        __syncthreads();
        gll16(a0 + kt * 32, lA);
        gll16(a1 + kt * 32, lA + 512);
        gll16(bsr + (size_t)kt * 4096,       lB);
        gll16(bsr + (size_t)kt * 4096 + 512, lB + 512);
        __syncthreads();
        f16x8 a[4], b[4];
#pragma unroll
        for (int i = 0; i < 4; ++i) a[i] = *(const f16x8*)(As + (wr*64 + i*16 + tq) * 32 + q * 8);
#pragma unroll
        for (int j = 0; j < 4; ++j) b[j] = *(const f16x8*)(Bs + (wc*64 + j*16 + tq) * 32 + q * 8);
#pragma unroll
        for (int i = 0; i < 4; ++i)
#pragma unroll
            for (int j = 0; j < 4; ++j)
                acc[i][j] = __builtin_amdgcn_mfma_f32_16x16x32_f16(b[j], a[i], acc[i][j], 0, 0, 0);
    }
#pragma unroll
    for (int i = 0; i < 4; ++i) {
        const int t = mt * 128 + wr * 64 + i * 16 + tq;
        unsigned short* hrow = H + (size_t)t * 512;
#pragma unroll
        for (int j = 0; j < 4; ++j) {
            const int cb = nt * 128 + wc * 64 + j * 16 + q * 4;
            float4 bv = *(const float4*)(bc1 + cb);
            f32x4 v = acc[i][j];
            unsigned short o[4] __attribute__((aligned(8)));
            o[0] = f2h(gelu_exact(v[0] + bv.x));
            o[1] = f2h(gelu_exact(v[1] + bv.y));
            o[2] = f2h(gelu_exact(v[2] + bv.z));
            o[3] = f2h(gelu_exact(v[3] + bv.w));
            *(uint2*)(hrow + cb) = *(uint2*)o;
        }
    }
}

// ---------------------------------------------------------------------------
// k_levels: logits = H @ Wc2 + bc2 (fp32), argmax; confident tokens compacted
// directly into idxb; small-margin tokens flagged for exact recompute.
// ---------------------------------------------------------------------------
__global__ __launch_bounds__(256) void k_levels(
    const unsigned short* __restrict__ H, const float* __restrict__ Wc2,
    const float* __restrict__ bc2, int* __restrict__ counts,
    int* __restrict__ idxb, int* __restrict__ flaglist, int* __restrict__ flagcnt)
{
    const int t    = (blockIdx.x * 256 + threadIdx.x) >> 6;
    const int lane = threadIdx.x & 63;
    const int j0   = lane * 8;

    const unsigned short* hrow = H + (size_t)t * 512 + j0;
    unsigned short hu[8] __attribute__((aligned(16)));
    *(uint4*)hu = *(const uint4*)hrow;

    float a0 = 0.f, a1 = 0.f, a2 = 0.f;
#pragma unroll
    for (int jj = 0; jj < 8; ++jj) {
        const float h = h2f(hu[jj]);
        const float* wr = Wc2 + (j0 + jj) * 3;
        a0 += h * wr[0]; a1 += h * wr[1]; a2 += h * wr[2];
    }
#pragma unroll
    for (int off = 32; off; off >>= 1) {
        a0 += __shfl_xor(a0, off);
        a1 += __shfl_xor(a1, off);
        a2 += __shfl_xor(a2, off);
    }
    if (lane == 0) {
        a0 += bc2[0]; a1 += bc2[1]; a2 += bc2[2];
        int lvl = 0; float best = a0;
        if (a1 > best) { best = a1; lvl = 1; }
        if (a2 > best) { best = a2; lvl = 2; }
        float second = (lvl == 0) ? fmaxf(a1, a2) : (lvl == 1) ? fmaxf(a0, a2) : fmaxf(a0, a1);
        if (best - second < MARGIN) {
            int pos = atomicAdd(flagcnt, 1);
            flaglist[pos] = t;
        } else {
            int pos = atomicAdd(&counts[lvl], 1);
            idxb[lvl * T_TOTAL + pos] = t;
        }
    }
}

// ---------------------------------------------------------------------------
// k_exact: exact fp32 classifier for flagged tokens (8/block, grid-stride);
// appends its tokens to idxb directly.
// ---------------------------------------------------------------------------
__global__ __launch_bounds__(256) void k_exact(
    const float* __restrict__ X, const float* __restrict__ Wc1,
    const float* __restrict__ bc1, const float* __restrict__ Wc2,
    const float* __restrict__ bc2, const int* __restrict__ flaglist,
    const int* __restrict__ flagcnt, int* __restrict__ counts,
    int* __restrict__ idxb)
{
    __shared__ float xs[1024][8];
    __shared__ float red[4][8][3];
    const int tid = threadIdx.x;
    const int nflag = flagcnt[0];

    for (int g = blockIdx.x; g * 8 < nflag; g += gridDim.x) {
        {
            const int s   = tid >> 5;
            const int l32 = tid & 31;
            int fi = g * 8 + s; if (fi >= nflag) fi = nflag - 1;
            const float* xr = X + (size_t)flaglist[fi] * DMODEL;
#pragma unroll
            for (int kk = 0; kk < 32; ++kk) {
                const int k = kk * 32 + l32;
                xs[k][s] = xr[k];
            }
        }
        __syncthreads();
        const int j = tid;
        float acc0[8], acc1[8];
#pragma unroll
        for (int s = 0; s < 8; ++s) { acc0[s] = 0.f; acc1[s] = 0.f; }
        for (int k = 0; k < 1024; ++k) {
            float4 xa = *(const float4*)&xs[k][0];
            float4 xb = *(const float4*)&xs[k][4];
            const float w0 = Wc1[(size_t)k * 512 + j];
            const float w1 = Wc1[(size_t)k * 512 + j + 256];
            acc0[0] += xa.x * w0; acc0[1] += xa.y * w0; acc0[2] += xa.z * w0; acc0[3] += xa.w * w0;
            acc0[4] += xb.x * w0; acc0[5] += xb.y * w0; acc0[6] += xb.z * w0; acc0[7] += xb.w * w0;
            acc1[0] += xa.x * w1; acc1[1] += xa.y * w1; acc1[2] += xa.z * w1; acc1[3] += xa.w * w1;
            acc1[4] += xb.x * w1; acc1[5] += xb.y * w1; acc1[6] += xb.z * w1; acc1[7] += xb.w * w1;
        }
        float p[8][3];
        {
            const float b0 = bc1[j], b1 = bc1[j + 256];
            const float* w2a = Wc2 + j * 3;
            const float* w2b = Wc2 + (j + 256) * 3;
#pragma unroll
            for (int s = 0; s < 8; ++s) {
                const float h0 = gelu_exact(acc0[s] + b0);
                const float h1 = gelu_exact(acc1[s] + b1);
                p[s][0] = h0 * w2a[0] + h1 * w2b[0];
                p[s][1] = h0 * w2a[1] + h1 * w2b[1];
                p[s][2] = h0 * w2a[2] + h1 * w2b[2];
            }
        }
#pragma unroll
        for (int off = 32; off; off >>= 1)
#pragma unroll
            for (int s = 0; s < 8; ++s) {
                p[s][0] += __shfl_xor(p[s][0], off);
                p[s][1] += __shfl_xor(p[s][1], off);
                p[s][2] += __shfl_xor(p[s][2], off);
            }
        if ((tid & 63) == 0) {
            const int w = tid >> 6;
#pragma unroll
            for (int s = 0; s < 8; ++s) {
                red[w][s][0] = p[s][0]; red[w][s][1] = p[s][1]; red[w][s][2] = p[s][2];
            }
        }
        __syncthreads();
        if (tid < 8) {
            const int fi = g * 8 + tid;
            if (fi < nflag) {
                float l0 = bc2[0], l1 = bc2[1], l2 = bc2[2];
#pragma unroll
                for (int w = 0; w < 4; ++w) {
                    l0 += red[w][tid][0]; l1 += red[w][tid][1]; l2 += red[w][tid][2];
                }
                int lvl = 0; float best = l0;
                if (l1 > best) { best = l1; lvl = 1; }
                if (l2 > best) { best = l2; lvl = 2; }
                const int tok = flaglist[fi];
                const int pos = atomicAdd(&counts[lvl], 1);
                idxb[lvl * T_TOTAL + pos] = tok;
            }
        }
        __syncthreads();
    }
}

// ---------------------------------------------------------------------------
__global__ void k_offsets(const int* __restrict__ counts, int* __restrict__ off,
                          int h0, int h1, int h2)
{
    if (threadIdx.x == 0 && blockIdx.x == 0) {
        off[0] = 0;
        off[1] = counts[0] * h0;
        off[2] = counts[0] * h0 + counts[1] * h1;
    }
}

// ---------------------------------------------------------------------------
// k_ffn1: Hmid = f16(GELU(Xh_gathered @ W1 + b1)), merged levels, m97-style.
// Each lane's two A-rows are fixed -> gathered token addresses precomputed.
// ---------------------------------------------------------------------------
struct FfnP1 {
    const unsigned short *Wq0, *Wq1, *Wq2;
    const float *bb0, *bb1, *bb2;
    const int* counts; const int* off; const int* idx;
    int s0, s01;
    int NT0, NT1, NT2;
    int st0, st1, st2;
    int no0;
};

__global__ __launch_bounds__(256) void k_ffn1(
    const unsigned short* __restrict__ Xh, unsigned short* __restrict__ Hmid, FfnP1 p)
{
    const int bid = swz_bid();
    int l, r;
    if (bid < p.s0)       { l = 0; r = bid; }
    else if (bid < p.s01) { l = 1; r = bid - p.s0; }
    else                  { l = 2; r = bid - p.s01; }
    const int NT = SEL3(l, p.NT0, p.NT1, p.NT2);
    const int mt = r / NT, nt = r % NT;
    const int n  = p.counts[l];
    if (mt * 128 >= n) return;

    const int* idx = p.idx + l * T_TOTAL;
    const unsigned short* Wq = SEL3(l, p.Wq0, p.Wq1, p.Wq2);
    const float* bb = SEL3(l, p.bb0, p.bb1, p.bb2);
    const int stride = SEL3(l, p.st0, p.st1, p.st2);
    const size_t hoff = (size_t)p.off[l];

    __shared__ __align__(16) unsigned short As[128 * 32];
    __shared__ __align__(16) unsigned short Bs[128 * 32];

    const int tid = threadIdx.x;
    const int w = tid >> 6, ln = tid & 63;
    const int wr = w >> 1, wc = w & 1;
    const int q = ln >> 4, tq = ln & 15;

    f32x4 acc[4][4];
#pragma unroll
    for (int i = 0; i < 4; ++i)
#pragma unroll
        for (int j = 0; j < 4; ++j) acc[i][j] = (f32x4){0.f, 0.f, 0.f, 0.f};

    int r0 = mt * 128 + w * 32 + (ln >> 2);
    int r1 = r0 + 16;
    if (r0 >= n) r0 = n - 1;
    if (r1 >= n) r1 = n - 1;
    const unsigned short* a0 = Xh + (size_t)idx[r0] * DMODEL + (ln & 3) * 8;
    const unsigned short* a1 = Xh + (size_t)idx[r1] * DMODEL + (ln & 3) * 8;
    const unsigned short* bsr = Wq + (size_t)(p.no0 + nt) * 32 * 4096 + w * 1024 + ln * 8;
    unsigned short* lA = As + w * 1024;
    unsigned short* lB = Bs + w * 1024;

    for (int kt = 0; kt < 32; ++kt) {
        __syncthreads();
        gll16(a0 + kt * 32, lA);
        gll16(a1 + kt * 32, lA + 512);
        gll16(bsr + (size_t)kt * 4096,       lB);
        gll16(bsr + (size_t)kt * 4096 + 512, lB + 512);
        __syncthreads();
        f16x8 a[4], b[4];
#pragma unroll
        for (int i = 0; i < 4; ++i) a[i] = *(const f16x8*)(As + (wr*64 + i*16 + tq) * 32 + q * 8);
#pragma unroll
        for (int j = 0; j < 4; ++j) b[j] = *(const f16x8*)(Bs + (wc*64 + j*16 + tq) * 32 + q * 8);
#pragma unroll
        for (int i = 0; i < 4; ++i)
#pragma unroll
            for (int j = 0; j < 4; ++j)
                acc[i][j] = __builtin_amdgcn_mfma_f32_16x16x32_f16(b[j], a[i], acc[i][j], 0, 0, 0);
    }
#pragma unroll
    for (int i = 0; i < 4; ++i) {
        const int pp = mt * 128 + wr * 64 + i * 16 + tq;
        if (pp < n) {
            unsigned short* hrow = Hmid + hoff + (size_t)pp * stride;
#pragma unroll
            for (int j = 0; j < 4; ++j) {
                const int cb = nt * 128 + wc * 64 + j * 16 + q * 4;
                float4 bv = *(const float4*)(bb + p.no0 * 128 + cb);
                f32x4 v = acc[i][j];
                unsigned short o[4] __attribute__((aligned(8)));
                o[0] = f2h(gelu_exact(v[0] + bv.x));
                o[1] = f2h(gelu_exact(v[1] + bv.y));
                o[2] = f2h(gelu_exact(v[2] + bv.z));
                o[3] = f2h(gelu_exact(v[3] + bv.w));
                *(uint2*)(hrow + cb) = *(uint2*)o;
            }
        }
    }
}

// ---------------------------------------------------------------------------
// k_ffn2: out = Hmid @ W2 + b2 (scatter), merged levels, m97-style.
// Work ordering: level 2 (K=4096) FIRST, then 1, then 0 — longest blocks
// start earliest on every XCD (kills the level-2 tail).
// ---------------------------------------------------------------------------
struct FfnP2 {
    const unsigned short *Wq0, *Wq1, *Wq2;
    const float *bb0, *bb1, *bb2;
    const int* counts; const int* off; const int* idx;
    int s2, s21;              // [0,s2)=level2, [s2,s21)=level1, [s21,..)=level0
    int st0, st1, st2;
    int kb;
    int kc0, kc1, kc2;
    int nf0, nf1, nf2;
    int accum;
};

__global__ __launch_bounds__(256) void k_ffn2(
    const unsigned short* __restrict__ Hmid, float* __restrict__ out, FfnP2 p)
{
    const int bid = swz_bid();
    int l, r;
    if (bid < p.s2)       { l = 2; r = bid; }
    else if (bid < p.s21) { l = 1; r = bid - p.s2; }
    else                  { l = 0; r = bid - p.s21; }
    const int mt = r >> 3, nt = r & 7;
    const int n  = p.counts[l];
    if (mt * 128 >= n) return;

    const int* idx = p.idx + l * T_TOTAL;
    const unsigned short* Wq = SEL3(l, p.Wq0, p.Wq1, p.Wq2);
    const float* bb = SEL3(l, p.bb0, p.bb1, p.bb2);
    const int stride = SEL3(l, p.st0, p.st1, p.st2);
    const int KC = SEL3(l, p.kc0, p.kc1, p.kc2);
    const int nf = SEL3(l, p.nf0, p.nf1, p.nf2);
    const size_t hoff = (size_t)p.off[l];

    __shared__ __align__(16) unsigned short As[128 * 32];
    __shared__ __align__(16) unsigned short Bs[128 * 32];

    const int tid = threadIdx.x;
    const int w = tid >> 6, ln = tid & 63;
    const int wr = w >> 1, wc = w & 1;
    const int q = ln >> 4, tq = ln & 15;

    f32x4 acc[4][4];
#pragma unroll
    for (int i = 0; i < 4; ++i)
#pragma unroll
        for (int j = 0; j < 4; ++j) acc[i][j] = (f32x4){0.f, 0.f, 0.f, 0.f};

    int r0 = mt * 128 + w * 32 + (ln >> 2);
    int r1 = r0 + 16;
    if (r0 >= n) r0 = n - 1;
    if (r1 >= n) r1 = n - 1;
    const unsigned short* a0 = Hmid + hoff + (size_t)r0 * stride + (ln & 3) * 8;
    const unsigned short* a1 = Hmid + hoff + (size_t)r1 * stride + (ln & 3) * 8;
    const unsigned short* bsr = Wq + ((size_t)nt * nf + p.kb) * 4096 + w * 1024 + ln * 8;
    unsigned short* lA = As + w * 1024;
    unsigned short* lB = Bs + w * 1024;

    for (int kt = 0; kt < KC; ++kt) {
        __syncthreads();
        gll16(a0 + kt * 32, lA);
        gll16(a1 + kt * 32, lA + 512);
        gll16(bsr + (size_t)kt * 4096,       lB);
        gll16(bsr + (size_t)kt * 4096 + 512, lB + 512);
        __syncthreads();
        f16x8 a[4], b[4];
#pragma unroll
        for (int i = 0; i < 4; ++i) a[i] = *(const f16x8*)(As + (wr*64 + i*16 + tq) * 32 + q * 8);
#pragma unroll
        for (int j = 0; j < 4; ++j) b[j] = *(const f16x8*)(Bs + (wc*64 + j*16 + tq) * 32 + q * 8);
#pragma unroll
        for (int i = 0; i < 4; ++i)
#pragma unroll
            for (int j = 0; j < 4; ++j)
                acc[i][j] = __builtin_amdgcn_mfma_f32_16x16x32_f16(b[j], a[i], acc[i][j], 0, 0, 0);
    }
#pragma unroll
    for (int i = 0; i < 4; ++i) {
        const int pp = mt * 128 + wr * 64 + i * 16 + tq;
        if (pp < n) {
            float* orow = out + (size_t)idx[pp] * DMODEL;
#pragma unroll
            for (int j = 0; j < 4; ++j) {
                const int cb = nt * 128 + wc * 64 + j * 16 + q * 4;
                f32x4 v = acc[i][j];
                float4 res;
                if (p.accum) {
                    float4 cur = *(const float4*)(orow + cb);
                    res.x = cur.x + v[0]; res.y = cur.y + v[1];
                    res.z = cur.z + v[2]; res.w = cur.w + v[3];
                } else {
                    float4 bv = *(const float4*)(bb + cb);
                    res.x = v[0] + bv.x; res.y = v[1] + bv.y;
                    res.z = v[2] + bv.z; res.w = v[3] + bv.w;
                }
                *(float4*)(orow + cb) = res;
            }
        }
    }
}

// ---------------------------------------------------------------------------
extern "C" void kernel_launch(void* const* d_in, const int* in_sizes, int n_in,
                              void* d_out, int out_size, void* d_ws, size_t ws_size,
                              hipStream_t stream)
{
    (void)in_sizes; (void)n_in; (void)out_size;

    const float* X   = (const float*)d_in[0];
    const float* Wc1 = (const float*)d_in[1];
    const float* bc1 = (const float*)d_in[2];
    const float* Wc2 = (const float*)d_in[3];
    const float* bc2 = (const float*)d_in[4];
    const float* W1[3] = {(const float*)d_in[5],  (const float*)d_in[9],  (const float*)d_in[13]};
    const float* b1[3] = {(const float*)d_in[6],  (const float*)d_in[10], (const float*)d_in[14]};
    const float* W2[3] = {(const float*)d_in[7],  (const float*)d_in[11], (const float*)d_in[15]};
    const float* b2[3] = {(const float*)d_in[8],  (const float*)d_in[12], (const float*)d_in[16]};
    float* out = (float*)d_out;
    const int FF[3] = {1024, 2048, 4096};

    // ---- workspace layout (Hmid last, sized to what remains) ----
    char* w = (char*)d_ws;
    size_t o = 0;
    auto take = [&](size_t bytes) -> char* {
        char* p = w + o;
        o = (o + bytes + 255) & ~(size_t)255;
        return p;
    };
    unsigned short* W1p[3]; for (int l = 0; l < 3; ++l) W1p[l] = (unsigned short*)take((size_t)1024 * FF[l] * 2);
    unsigned short* W2p[3]; for (int l = 0; l < 3; ++l) W2p[l] = (unsigned short*)take((size_t)1024 * FF[l] * 2);
    unsigned short* Wc1p = (unsigned short*)take((size_t)1024 * 512 * 2);
    unsigned short* Xh   = (unsigned short*)take((size_t)T_TOTAL * DMODEL * 2);
    unsigned short* H    = (unsigned short*)take((size_t)T_TOTAL * 512 * 2);
    int* flaglist = (int*)take((size_t)T_TOTAL * 4);
    int* idxb     = (int*)take((size_t)3 * T_TOTAL * 4);
    int* ctrs     = (int*)take(256);   // [0..2]=counts, [8]=flagcnt, [16..18]=off
    unsigned short* Hmid = (unsigned short*)(w + o);
    const size_t avail = ws_size > o ? ws_size - o : 0;

    int CHUNK = 256;
    const int cand[4] = {4096, 2048, 1024, 512};
    for (int ci = 0; ci < 4; ++ci)
        if ((size_t)T_TOTAL * cand[ci] * 2 <= avail) { CHUNK = cand[ci]; break; }
    int HC[3]; for (int l = 0; l < 3; ++l) HC[l] = FF[l] < CHUNK ? FF[l] : CHUNK;

    // ---- convert + pack (all 7 packs in one launch) ----
    k_cvt<<<(T_TOTAL * DMODEL) / (256 * 8), 256, 0, stream>>>(X, Xh);
    {
        PackP pk;
        int ob = 0, slot = 0;
        auto addpk = [&](const float* s, unsigned short* d2, int K, int N) {
            pk.src[slot] = s; pk.dst[slot] = d2; pk.K[slot] = K; pk.N[slot] = N;
            pk.boff[slot] = ob; ob += (N / 128) * (K / 32); ++slot;
        };
        for (int l = 0; l < 3; ++l) addpk(W1[l], W1p[l], 1024, FF[l]);
        for (int l = 0; l < 3; ++l) addpk(W2[l], W2p[l], FF[l], 1024);
        addpk(Wc1, Wc1p, 1024, 512);
        pk.boff[7] = ob;
        k_pack_all<<<ob, 256, 0, stream>>>(pk);
    }

    // ---- classifier + routing (compaction fused into levels/exact) ----
    k_h<<<(T_TOTAL / 128) * 4, 256, 0, stream>>>(Xh, Wc1p, bc1, H);
    hipMemsetAsync(ctrs, 0, 256, stream);
    k_levels<<<T_TOTAL / 4, 256, 0, stream>>>(H, Wc2, bc2, ctrs, idxb, flaglist, ctrs + 8);
    k_exact<<<128, 256, 0, stream>>>(X, Wc1, bc1, Wc2, bc2, flaglist, ctrs + 8, ctrs, idxb);
    k_offsets<<<1, 64, 0, stream>>>(ctrs, ctrs + 16, HC[0], HC[1], HC[2]);

    // ---- FFN: merged-level launches, chunked only if ws forces it ----
    const int nchunks = FF[2] / CHUNK;
    for (int c = 0; c < nchunks; ++c) {
        int NTc[3];
        for (int l = 0; l < 3; ++l) {
            int rem = FF[l] - c * CHUNK;
            NTc[l] = rem > 0 ? (rem < CHUNK ? rem : CHUNK) / 128 : 0;
        }
        const int g1_0 = 128 * NTc[0], g1_1 = 128 * NTc[1], g1_2 = 128 * NTc[2];
        const int G1 = g1_0 + g1_1 + g1_2;
        const int g2_0 = NTc[0] ? 1024 : 0, g2_1 = NTc[1] ? 1024 : 0, g2_2 = NTc[2] ? 1024 : 0;
        const int G2 = g2_0 + g2_1 + g2_2;
        if (G1 == 0) continue;

        FfnP1 p1;
        p1.Wq0 = W1p[0]; p1.Wq1 = W1p[1]; p1.Wq2 = W1p[2];
        p1.bb0 = b1[0];  p1.bb1 = b1[1];  p1.bb2 = b1[2];
        p1.counts = ctrs; p1.off = ctrs + 16; p1.idx = idxb;
        p1.s0 = g1_0; p1.s01 = g1_0 + g1_1;
        p1.NT0 = NTc[0]; p1.NT1 = NTc[1]; p1.NT2 = NTc[2];
        p1.st0 = HC[0]; p1.st1 = HC[1]; p1.st2 = HC[2];
        p1.no0 = c * CHUNK / 128;
        k_ffn1<<<G1, 256, 0, stream>>>(Xh, Hmid, p1);

        FfnP2 p2;
        p2.Wq0 = W2p[0]; p2.Wq1 = W2p[1]; p2.Wq2 = W2p[2];
        p2.bb0 = b2[0];  p2.bb1 = b2[1];  p2.bb2 = b2[2];
        p2.counts = ctrs; p2.off = ctrs + 16; p2.idx = idxb;
        p2.s2 = g2_2; p2.s21 = g2_2 + g2_1;
        p2.st0 = HC[0]; p2.st1 = HC[1]; p2.st2 = HC[2];
        p2.kb = c * CHUNK / 32;
        p2.kc0 = NTc[0] * 4; p2.kc1 = NTc[1] * 4; p2.kc2 = NTc[2] * 4;
        p2.nf0 = FF[0] / 32; p2.nf1 = FF[1] / 32; p2.nf2 = FF[2] / 32;
        p2.accum = (c > 0) ? 1 : 0;
        k_ffn2<<<G2, 256, 0, stream>>>(Hmid, out, p2);
    }
}

// Round 2
// 579.540 us; speedup vs baseline: 1.2903x; 1.2903x over previous
//
#include <hip/hip_runtime.h>
#include <math.h>

#define T_TOTAL 16384
#define DMODEL  1024
#define MARGIN  2.5e-3f

typedef __attribute__((ext_vector_type(8))) _Float16 f16x8;
typedef __attribute__((ext_vector_type(4))) float    f32x4;

#define SEL3(l, a, b, c) ((l) == 0 ? (a) : (l) == 1 ? (b) : (c))

// counters padded to separate 128B lines: count[l] at ctrs[l*32], flagcnt at
// ctrs[96], offsets at ctrs[128..130].
#define CTR_STRIDE 32

__device__ __forceinline__ float gelu_exact(float x) {
    return 0.5f * x * (1.0f + erff(x * 0.7071067811865476f));
}
__device__ __forceinline__ unsigned short f2h(float f) {
    union { _Float16 h; unsigned short s; } c; c.h = (_Float16)f; return c.s;
}
__device__ __forceinline__ float h2f(unsigned short u) {
    union { unsigned short s; _Float16 h; } c; c.s = u; return (float)c.h;
}
// async global->LDS, 16B per lane; LDS dest = wave-uniform base + lane*16.
__device__ __forceinline__ void gll16(const void* g, void* l) {
    __builtin_amdgcn_global_load_lds(
        (const __attribute__((address_space(1))) unsigned int*)g,
        (__attribute__((address_space(3))) unsigned int*)l, 16, 0, 0);
}

// Panel-chunked XCD swizzle (bijective when gridDim.x % 64 == 0).
__device__ __forceinline__ int swz_bid() {
    const int b = blockIdx.x;
    const int G = gridDim.x;
    if (G & 63) return b;
    const int x = b & 7, j = b >> 3;
    return (x + 8 * (j >> 3)) * 8 + (j & 7);
}

// ---------------------------------------------------------------------------
// k_cvt: Xh = f16(X), whole tensor. 8 floats/thread.
// ---------------------------------------------------------------------------
__global__ __launch_bounds__(256) void k_cvt(
    const float* __restrict__ X, unsigned short* __restrict__ Xh)
{
    const size_t i = ((size_t)blockIdx.x * 256 + threadIdx.x) * 8;
    float4 f0 = *(const float4*)(X + i);
    float4 f1 = *(const float4*)(X + i + 4);
    unsigned short o[8] __attribute__((aligned(16)));
    o[0]=f2h(f0.x); o[1]=f2h(f0.y); o[2]=f2h(f0.z); o[3]=f2h(f0.w);
    o[4]=f2h(f1.x); o[5]=f2h(f1.y); o[6]=f2h(f1.z); o[7]=f2h(f1.w);
    *(uint4*)(Xh + i) = *(uint4*)o;
}

// ---------------------------------------------------------------------------
// k_pack_all: pack all 7 fp32 weights [K][N] into f16 tiles
// [N/128][K/32][128][32] in ONE launch. tile[r][c] = W[kt*32+c][nt*128+r].
// ---------------------------------------------------------------------------
struct PackP {
    const float* src[7];
    unsigned short* dst[7];
    int K[7], N[7];
    int boff[8];
};

__global__ __launch_bounds__(256) void k_pack_all(PackP p)
{
    const int gb = blockIdx.x;
    int t = 0;
    while (t < 6 && gb >= p.boff[t + 1]) ++t;
    const int lb = gb - p.boff[t];
    const float* src = p.src[t];
    unsigned short* dst = p.dst[t];
    const int K = p.K[t], N = p.N[t];

    const int ktiles = K >> 5;
    const int nt = lb / ktiles;
    const int kt = lb % ktiles;
    __shared__ float ls[32][129];
    const int tid = threadIdx.x;
    {
        const int c  = tid >> 3;
        const int n0 = (tid & 7) * 16;
        const float* s = src + (size_t)(kt * 32 + c) * N + (size_t)nt * 128 + n0;
#pragma unroll
        for (int v = 0; v < 4; ++v) {
            float4 f = *(const float4*)(s + v * 4);
            ls[c][n0 + v*4 + 0] = f.x; ls[c][n0 + v*4 + 1] = f.y;
            ls[c][n0 + v*4 + 2] = f.z; ls[c][n0 + v*4 + 3] = f.w;
        }
    }
    __syncthreads();
    {
        const int r  = tid >> 1;
        const int c0 = (tid & 1) * 16;
        unsigned short tmp[16] __attribute__((aligned(16)));
#pragma unroll
        for (int c = 0; c < 16; ++c) tmp[c] = f2h(ls[c0 + c][r]);
        unsigned short* d = dst + (size_t)lb * (128 * 32) + r * 32 + c0;
        *(uint4*)(d)     = *(uint4*)&tmp[0];
        *(uint4*)(d + 8) = *(uint4*)&tmp[8];
    }
}

// ---------------------------------------------------------------------------
// k_h: H = f16( GELU(Xh @ Wc1 + bc1) ), m97-style. [16384x1024]@[1024x512].
// ---------------------------------------------------------------------------
__global__ __launch_bounds__(256) void k_h(
    const unsigned short* __restrict__ Xh, const unsigned short* __restrict__ Wq,
    const float* __restrict__ bc1, unsigned short* __restrict__ H)
{
    const int bid = swz_bid();
    const int mt = bid >> 2;
    const int nt = bid & 3;
    __shared__ __align__(16) unsigned short As[128 * 32];
    __shared__ __align__(16) unsigned short Bs[128 * 32];

    const int tid = threadIdx.x;
    const int w = tid >> 6, ln = tid & 63;
    const int wr = w >> 1, wc = w & 1;
    const int q = ln >> 4, tq = ln & 15;

    f32x4 acc[4][4];
#pragma unroll
    for (int i = 0; i < 4; ++i)
#pragma unroll
        for (int j = 0; j < 4; ++j) acc[i][j] = (f32x4){0.f, 0.f, 0.f, 0.f};

    const int r0 = mt * 128 + w * 32 + (ln >> 2);
    const unsigned short* a0 = Xh + (size_t)r0 * DMODEL + (ln & 3) * 8;
    const unsigned short* a1 = a0 + (size_t)16 * DMODEL;
    const unsigned short* bsr = Wq + (size_t)nt * 32 * 4096 + w * 1024 + ln * 8;
    unsigned short* lA = As + w * 1024;
    unsigned short* lB = Bs + w * 1024;

    for (int kt = 0; kt < 32; ++kt) {
        __syncthreads();
        gll16(a0 + kt * 32, lA);
        gll16(a1 + kt * 32, lA + 512);
        gll16(bsr + (size_t)kt * 4096,       lB);
        gll16(bsr + (size_t)kt * 4096 + 512, lB + 512);
        __syncthreads();
        f16x8 a[4], b[4];
#pragma unroll
        for (int i = 0; i < 4; ++i) a[i] = *(const f16x8*)(As + (wr*64 + i*16 + tq) * 32 + q * 8);
#pragma unroll
        for (int j = 0; j < 4; ++j) b[j] = *(const f16x8*)(Bs + (wc*64 + j*16 + tq) * 32 + q * 8);
#pragma unroll
        for (int i = 0; i < 4; ++i)
#pragma unroll
            for (int j = 0; j < 4; ++j)
                acc[i][j] = __builtin_amdgcn_mfma_f32_16x16x32_f16(b[j], a[i], acc[i][j], 0, 0, 0);
    }
#pragma unroll
    for (int i = 0; i < 4; ++i) {
        const int t = mt * 128 + wr * 64 + i * 16 + tq;
        unsigned short* hrow = H + (size_t)t * 512;
#pragma unroll
        for (int j = 0; j < 4; ++j) {
            const int cb = nt * 128 + wc * 64 + j * 16 + q * 4;
            float4 bv = *(const float4*)(bc1 + cb);
            f32x4 v = acc[i][j];
            unsigned short o[4] __attribute__((aligned(8)));
            o[0] = f2h(gelu_exact(v[0] + bv.x));
            o[1] = f2h(gelu_exact(v[1] + bv.y));
            o[2] = f2h(gelu_exact(v[2] + bv.z));
            o[3] = f2h(gelu_exact(v[3] + bv.w));
            *(uint2*)(hrow + cb) = *(uint2*)o;
        }
    }
}

// ---------------------------------------------------------------------------
// k_levels: logits = H @ Wc2 + bc2 (fp32), argmax. 64 tokens/block; levels
// staged in LDS; block-level ballot compaction -> ONE atomicAdd per
// (block, level) on 128B-padded counters. Small-margin tokens -> flaglist.
// ---------------------------------------------------------------------------
__global__ __launch_bounds__(256) void k_levels(
    const unsigned short* __restrict__ H, const float* __restrict__ Wc2,
    const float* __restrict__ bc2, int* __restrict__ ctrs,
    int* __restrict__ idxb, int* __restrict__ flaglist)
{
    __shared__ int lvlbuf[64];
    const int tid  = threadIdx.x;
    const int wv   = tid >> 6, lane = tid & 63;
    const int t0   = blockIdx.x * 64;
    const int j0   = lane * 8;

    // hoist this lane's 24 Wc2 coefficients (rows j0..j0+7)
    float wa[8], wb[8], wc[8];
#pragma unroll
    for (int jj = 0; jj < 8; ++jj) {
        const float* wr = Wc2 + (j0 + jj) * 3;
        wa[jj] = wr[0]; wb[jj] = wr[1]; wc[jj] = wr[2];
    }
    const float bz0 = bc2[0], bz1 = bc2[1], bz2 = bc2[2];

    for (int it = 0; it < 16; ++it) {
        const int t = t0 + wv * 16 + it;
        const unsigned short* hrow = H + (size_t)t * 512 + j0;
        unsigned short hu[8] __attribute__((aligned(16)));
        *(uint4*)hu = *(const uint4*)hrow;

        float a0 = 0.f, a1 = 0.f, a2 = 0.f;
#pragma unroll
        for (int jj = 0; jj < 8; ++jj) {
            const float h = h2f(hu[jj]);
            a0 += h * wa[jj]; a1 += h * wb[jj]; a2 += h * wc[jj];
        }
#pragma unroll
        for (int off = 32; off; off >>= 1) {
            a0 += __shfl_xor(a0, off);
            a1 += __shfl_xor(a1, off);
            a2 += __shfl_xor(a2, off);
        }
        if (lane == 0) {
            a0 += bz0; a1 += bz1; a2 += bz2;
            int lvl = 0; float best = a0;
            if (a1 > best) { best = a1; lvl = 1; }
            if (a2 > best) { best = a2; lvl = 2; }
            float second = (lvl == 0) ? fmaxf(a1, a2) : (lvl == 1) ? fmaxf(a0, a2) : fmaxf(a0, a1);
            lvlbuf[wv * 16 + it] = (best - second < MARGIN) ? 3 : lvl;
        }
    }
    __syncthreads();
    // wave 0 compacts all 64 tokens: one atomic per level per block.
    if (tid < 64) {
        const int mylvl = lvlbuf[tid];
        const int mytok = t0 + tid;
#pragma unroll
        for (int lvl = 0; lvl < 4; ++lvl) {
            const unsigned long long m = __ballot(mylvl == lvl);
            int base = 0;
            if (tid == 0) {
                const int cnt = __popcll(m);
                if (cnt) base = atomicAdd(&ctrs[lvl * CTR_STRIDE], cnt);
            }
            base = __shfl(base, 0);
            if (mylvl == lvl) {
                const int pos = base + __popcll(m & ((1ull << tid) - 1ull));
                if (lvl < 3) idxb[lvl * T_TOTAL + pos] = mytok;
                else         flaglist[pos] = mytok;
            }
        }
    }
}

// ---------------------------------------------------------------------------
// k_exact: exact fp32 classifier for flagged tokens (8/block, grid-stride);
// appends its tokens to idxb directly (nflag is tiny -> low contention).
// ---------------------------------------------------------------------------
__global__ __launch_bounds__(256) void k_exact(
    const float* __restrict__ X, const float* __restrict__ Wc1,
    const float* __restrict__ bc1, const float* __restrict__ Wc2,
    const float* __restrict__ bc2, const int* __restrict__ flaglist,
    const int* __restrict__ flagcnt, int* __restrict__ ctrs,
    int* __restrict__ idxb)
{
    __shared__ float xs[1024][8];
    __shared__ float red[4][8][3];
    const int tid = threadIdx.x;
    const int nflag = flagcnt[0];

    for (int g = blockIdx.x; g * 8 < nflag; g += gridDim.x) {
        {
            const int s   = tid >> 5;
            const int l32 = tid & 31;
            int fi = g * 8 + s; if (fi >= nflag) fi = nflag - 1;
            const float* xr = X + (size_t)flaglist[fi] * DMODEL;
#pragma unroll
            for (int kk = 0; kk < 32; ++kk) {
                const int k = kk * 32 + l32;
                xs[k][s] = xr[k];
            }
        }
        __syncthreads();
        const int j = tid;
        float acc0[8], acc1[8];
#pragma unroll
        for (int s = 0; s < 8; ++s) { acc0[s] = 0.f; acc1[s] = 0.f; }
        for (int k = 0; k < 1024; ++k) {
            float4 xa = *(const float4*)&xs[k][0];
            float4 xb = *(const float4*)&xs[k][4];
            const float w0 = Wc1[(size_t)k * 512 + j];
            const float w1 = Wc1[(size_t)k * 512 + j + 256];
            acc0[0] += xa.x * w0; acc0[1] += xa.y * w0; acc0[2] += xa.z * w0; acc0[3] += xa.w * w0;
            acc0[4] += xb.x * w0; acc0[5] += xb.y * w0; acc0[6] += xb.z * w0; acc0[7] += xb.w * w0;
            acc1[0] += xa.x * w1; acc1[1] += xa.y * w1; acc1[2] += xa.z * w1; acc1[3] += xa.w * w1;
            acc1[4] += xb.x * w1; acc1[5] += xb.y * w1; acc1[6] += xb.z * w1; acc1[7] += xb.w * w1;
        }
        float p[8][3];
        {
            const float b0 = bc1[j], b1 = bc1[j + 256];
            const float* w2a = Wc2 + j * 3;
            const float* w2b = Wc2 + (j + 256) * 3;
#pragma unroll
            for (int s = 0; s < 8; ++s) {
                const float h0 = gelu_exact(acc0[s] + b0);
                const float h1 = gelu_exact(acc1[s] + b1);
                p[s][0] = h0 * w2a[0] + h1 * w2b[0];
                p[s][1] = h0 * w2a[1] + h1 * w2b[1];
                p[s][2] = h0 * w2a[2] + h1 * w2b[2];
            }
        }
#pragma unroll
        for (int off = 32; off; off >>= 1)
#pragma unroll
            for (int s = 0; s < 8; ++s) {
                p[s][0] += __shfl_xor(p[s][0], off);
                p[s][1] += __shfl_xor(p[s][1], off);
                p[s][2] += __shfl_xor(p[s][2], off);
            }
        if ((tid & 63) == 0) {
            const int w = tid >> 6;
#pragma unroll
            for (int s = 0; s < 8; ++s) {
                red[w][s][0] = p[s][0]; red[w][s][1] = p[s][1]; red[w][s][2] = p[s][2];
            }
        }
        __syncthreads();
        if (tid < 8) {
            const int fi = g * 8 + tid;
            if (fi < nflag) {
                float l0 = bc2[0], l1 = bc2[1], l2 = bc2[2];
#pragma unroll
                for (int w = 0; w < 4; ++w) {
                    l0 += red[w][tid][0]; l1 += red[w][tid][1]; l2 += red[w][tid][2];
                }
                int lvl = 0; float best = l0;
                if (l1 > best) { best = l1; lvl = 1; }
                if (l2 > best) { best = l2; lvl = 2; }
                const int tok = flaglist[fi];
                const int pos = atomicAdd(&ctrs[lvl * CTR_STRIDE], 1);
                idxb[lvl * T_TOTAL + pos] = tok;
            }
        }
        __syncthreads();
    }
}

// ---------------------------------------------------------------------------
__global__ void k_offsets(const int* __restrict__ ctrs, int* __restrict__ off,
                          int h0, int h1, int h2)
{
    if (threadIdx.x == 0 && blockIdx.x == 0) {
        off[0] = 0;
        off[1] = ctrs[0] * h0;
        off[2] = ctrs[0] * h0 + ctrs[CTR_STRIDE] * h1;
    }
}

// ---------------------------------------------------------------------------
// k_ffn1: Hmid = f16(GELU(Xh_gathered @ W1 + b1)), merged levels, m97-style.
// ---------------------------------------------------------------------------
struct FfnP1 {
    const unsigned short *Wq0, *Wq1, *Wq2;
    const float *bb0, *bb1, *bb2;
    const int* counts; const int* off; const int* idx;
    int s0, s01;
    int NT0, NT1, NT2;
    int st0, st1, st2;
    int no0;
};

__global__ __launch_bounds__(256) void k_ffn1(
    const unsigned short* __restrict__ Xh, unsigned short* __restrict__ Hmid, FfnP1 p)
{
    const int bid = swz_bid();
    int l, r;
    if (bid < p.s0)       { l = 0; r = bid; }
    else if (bid < p.s01) { l = 1; r = bid - p.s0; }
    else                  { l = 2; r = bid - p.s01; }
    const int NT = SEL3(l, p.NT0, p.NT1, p.NT2);
    const int mt = r / NT, nt = r % NT;
    const int n  = p.counts[l * CTR_STRIDE];
    if (mt * 128 >= n) return;

    const int* idx = p.idx + l * T_TOTAL;
    const unsigned short* Wq = SEL3(l, p.Wq0, p.Wq1, p.Wq2);
    const float* bb = SEL3(l, p.bb0, p.bb1, p.bb2);
    const int stride = SEL3(l, p.st0, p.st1, p.st2);
    const size_t hoff = (size_t)p.off[l];

    __shared__ __align__(16) unsigned short As[128 * 32];
    __shared__ __align__(16) unsigned short Bs[128 * 32];

    const int tid = threadIdx.x;
    const int w = tid >> 6, ln = tid & 63;
    const int wr = w >> 1, wc = w & 1;
    const int q = ln >> 4, tq = ln & 15;

    f32x4 acc[4][4];
#pragma unroll
    for (int i = 0; i < 4; ++i)
#pragma unroll
        for (int j = 0; j < 4; ++j) acc[i][j] = (f32x4){0.f, 0.f, 0.f, 0.f};

    int r0 = mt * 128 + w * 32 + (ln >> 2);
    int r1 = r0 + 16;
    if (r0 >= n) r0 = n - 1;
    if (r1 >= n) r1 = n - 1;
    const unsigned short* a0 = Xh + (size_t)idx[r0] * DMODEL + (ln & 3) * 8;
    const unsigned short* a1 = Xh + (size_t)idx[r1] * DMODEL + (ln & 3) * 8;
    const unsigned short* bsr = Wq + (size_t)(p.no0 + nt) * 32 * 4096 + w * 1024 + ln * 8;
    unsigned short* lA = As + w * 1024;
    unsigned short* lB = Bs + w * 1024;

    for (int kt = 0; kt < 32; ++kt) {
        __syncthreads();
        gll16(a0 + kt * 32, lA);
        gll16(a1 + kt * 32, lA + 512);
        gll16(bsr + (size_t)kt * 4096,       lB);
        gll16(bsr + (size_t)kt * 4096 + 512, lB + 512);
        __syncthreads();
        f16x8 a[4], b[4];
#pragma unroll
        for (int i = 0; i < 4; ++i) a[i] = *(const f16x8*)(As + (wr*64 + i*16 + tq) * 32 + q * 8);
#pragma unroll
        for (int j = 0; j < 4; ++j) b[j] = *(const f16x8*)(Bs + (wc*64 + j*16 + tq) * 32 + q * 8);
#pragma unroll
        for (int i = 0; i < 4; ++i)
#pragma unroll
            for (int j = 0; j < 4; ++j)
                acc[i][j] = __builtin_amdgcn_mfma_f32_16x16x32_f16(b[j], a[i], acc[i][j], 0, 0, 0);
    }
#pragma unroll
    for (int i = 0; i < 4; ++i) {
        const int pp = mt * 128 + wr * 64 + i * 16 + tq;
        if (pp < n) {
            unsigned short* hrow = Hmid + hoff + (size_t)pp * stride;
#pragma unroll
            for (int j = 0; j < 4; ++j) {
                const int cb = nt * 128 + wc * 64 + j * 16 + q * 4;
                float4 bv = *(const float4*)(bb + p.no0 * 128 + cb);
                f32x4 v = acc[i][j];
                unsigned short o[4] __attribute__((aligned(8)));
                o[0] = f2h(gelu_exact(v[0] + bv.x));
                o[1] = f2h(gelu_exact(v[1] + bv.y));
                o[2] = f2h(gelu_exact(v[2] + bv.z));
                o[3] = f2h(gelu_exact(v[3] + bv.w));
                *(uint2*)(hrow + cb) = *(uint2*)o;
            }
        }
    }
}

// ---------------------------------------------------------------------------
// k_ffn2: out = Hmid @ W2 + b2 (scatter), merged levels, m97-style.
// Work ordering: level 2 (K=4096) first, then 1, then 0.
// ---------------------------------------------------------------------------
struct FfnP2 {
    const unsigned short *Wq0, *Wq1, *Wq2;
    const float *bb0, *bb1, *bb2;
    const int* counts; const int* off; const int* idx;
    int s2, s21;              // [0,s2)=level2, [s2,s21)=level1, [s21,..)=level0
    int st0, st1, st2;
    int kb;
    int kc0, kc1, kc2;
    int nf0, nf1, nf2;
    int accum;
};

__global__ __launch_bounds__(256) void k_ffn2(
    const unsigned short* __restrict__ Hmid, float* __restrict__ out, FfnP2 p)
{
    const int bid = swz_bid();
    int l, r;
    if (bid < p.s2)       { l = 2; r = bid; }
    else if (bid < p.s21) { l = 1; r = bid - p.s2; }
    else                  { l = 0; r = bid - p.s21; }
    const int mt = r >> 3, nt = r & 7;
    const int n  = p.counts[l * CTR_STRIDE];
    if (mt * 128 >= n) return;

    const int* idx = p.idx + l * T_TOTAL;
    const unsigned short* Wq = SEL3(l, p.Wq0, p.Wq1, p.Wq2);
    const float* bb = SEL3(l, p.bb0, p.bb1, p.bb2);
    const int stride = SEL3(l, p.st0, p.st1, p.st2);
    const int KC = SEL3(l, p.kc0, p.kc1, p.kc2);
    const int nf = SEL3(l, p.nf0, p.nf1, p.nf2);
    const size_t hoff = (size_t)p.off[l];

    __shared__ __align__(16) unsigned short As[128 * 32];
    __shared__ __align__(16) unsigned short Bs[128 * 32];

    const int tid = threadIdx.x;
    const int w = tid >> 6, ln = tid & 63;
    const int wr = w >> 1, wc = w & 1;
    const int q = ln >> 4, tq = ln & 15;

    f32x4 acc[4][4];
#pragma unroll
    for (int i = 0; i < 4; ++i)
#pragma unroll
        for (int j = 0; j < 4; ++j) acc[i][j] = (f32x4){0.f, 0.f, 0.f, 0.f};

    int r0 = mt * 128 + w * 32 + (ln >> 2);
    int r1 = r0 + 16;
    if (r0 >= n) r0 = n - 1;
    if (r1 >= n) r1 = n - 1;
    const unsigned short* a0 = Hmid + hoff + (size_t)r0 * stride + (ln & 3) * 8;
    const unsigned short* a1 = Hmid + hoff + (size_t)r1 * stride + (ln & 3) * 8;
    const unsigned short* bsr = Wq + ((size_t)nt * nf + p.kb) * 4096 + w * 1024 + ln * 8;
    unsigned short* lA = As + w * 1024;
    unsigned short* lB = Bs + w * 1024;

    for (int kt = 0; kt < KC; ++kt) {
        __syncthreads();
        gll16(a0 + kt * 32, lA);
        gll16(a1 + kt * 32, lA + 512);
        gll16(bsr + (size_t)kt * 4096,       lB);
        gll16(bsr + (size_t)kt * 4096 + 512, lB + 512);
        __syncthreads();
        f16x8 a[4], b[4];
#pragma unroll
        for (int i = 0; i < 4; ++i) a[i] = *(const f16x8*)(As + (wr*64 + i*16 + tq) * 32 + q * 8);
#pragma unroll
        for (int j = 0; j < 4; ++j) b[j] = *(const f16x8*)(Bs + (wc*64 + j*16 + tq) * 32 + q * 8);
#pragma unroll
        for (int i = 0; i < 4; ++i)
#pragma unroll
            for (int j = 0; j < 4; ++j)
                acc[i][j] = __builtin_amdgcn_mfma_f32_16x16x32_f16(b[j], a[i], acc[i][j], 0, 0, 0);
    }
#pragma unroll
    for (int i = 0; i < 4; ++i) {
        const int pp = mt * 128 + wr * 64 + i * 16 + tq;
        if (pp < n) {
            float* orow = out + (size_t)idx[pp] * DMODEL;
#pragma unroll
            for (int j = 0; j < 4; ++j) {
                const int cb = nt * 128 + wc * 64 + j * 16 + q * 4;
                f32x4 v = acc[i][j];
                float4 res;
                if (p.accum) {
                    float4 cur = *(const float4*)(orow + cb);
                    res.x = cur.x + v[0]; res.y = cur.y + v[1];
                    res.z = cur.z + v[2]; res.w = cur.w + v[3];
                } else {
                    float4 bv = *(const float4*)(bb + cb);
                    res.x = v[0] + bv.x; res.y = v[1] + bv.y;
                    res.z = v[2] + bv.z; res.w = v[3] + bv.w;
                }
                *(float4*)(orow + cb) = res;
            }
        }
    }
}

// ---------------------------------------------------------------------------
extern "C" void kernel_launch(void* const* d_in, const int* in_sizes, int n_in,
                              void* d_out, int out_size, void* d_ws, size_t ws_size,
                              hipStream_t stream)
{
    (void)in_sizes; (void)n_in; (void)out_size;

    const float* X   = (const float*)d_in[0];
    const float* Wc1 = (const float*)d_in[1];
    const float* bc1 = (const float*)d_in[2];
    const float* Wc2 = (const float*)d_in[3];
    const float* bc2 = (const float*)d_in[4];
    const float* W1[3] = {(const float*)d_in[5],  (const float*)d_in[9],  (const float*)d_in[13]};
    const float* b1[3] = {(const float*)d_in[6],  (const float*)d_in[10], (const float*)d_in[14]};
    const float* W2[3] = {(const float*)d_in[7],  (const float*)d_in[11], (const float*)d_in[15]};
    const float* b2[3] = {(const float*)d_in[8],  (const float*)d_in[12], (const float*)d_in[16]};
    float* out = (float*)d_out;
    const int FF[3] = {1024, 2048, 4096};

    // ---- workspace layout (Hmid last, sized to what remains) ----
    char* w = (char*)d_ws;
    size_t o = 0;
    auto take = [&](size_t bytes) -> char* {
        char* p = w + o;
        o = (o + bytes + 255) & ~(size_t)255;
        return p;
    };
    unsigned short* W1p[3]; for (int l = 0; l < 3; ++l) W1p[l] = (unsigned short*)take((size_t)1024 * FF[l] * 2);
    unsigned short* W2p[3]; for (int l = 0; l < 3; ++l) W2p[l] = (unsigned short*)take((size_t)1024 * FF[l] * 2);
    unsigned short* Wc1p = (unsigned short*)take((size_t)1024 * 512 * 2);
    unsigned short* Xh   = (unsigned short*)take((size_t)T_TOTAL * DMODEL * 2);
    unsigned short* H    = (unsigned short*)take((size_t)T_TOTAL * 512 * 2);
    int* flaglist = (int*)take((size_t)T_TOTAL * 4);
    int* idxb     = (int*)take((size_t)3 * T_TOTAL * 4);
    int* ctrs     = (int*)take(1024);  // count[l]@l*32, flagcnt@96, off@128..130
    unsigned short* Hmid = (unsigned short*)(w + o);
    const size_t avail = ws_size > o ? ws_size - o : 0;

    int CHUNK = 256;
    const int cand[4] = {4096, 2048, 1024, 512};
    for (int ci = 0; ci < 4; ++ci)
        if ((size_t)T_TOTAL * cand[ci] * 2 <= avail) { CHUNK = cand[ci]; break; }
    int HC[3]; for (int l = 0; l < 3; ++l) HC[l] = FF[l] < CHUNK ? FF[l] : CHUNK;

    // ---- convert + pack (all 7 packs in one launch) ----
    k_cvt<<<(T_TOTAL * DMODEL) / (256 * 8), 256, 0, stream>>>(X, Xh);
    {
        PackP pk;
        int ob = 0, slot = 0;
        auto addpk = [&](const float* s, unsigned short* d2, int K, int N) {
            pk.src[slot] = s; pk.dst[slot] = d2; pk.K[slot] = K; pk.N[slot] = N;
            pk.boff[slot] = ob; ob += (N / 128) * (K / 32); ++slot;
        };
        for (int l = 0; l < 3; ++l) addpk(W1[l], W1p[l], 1024, FF[l]);
        for (int l = 0; l < 3; ++l) addpk(W2[l], W2p[l], FF[l], 1024);
        addpk(Wc1, Wc1p, 1024, 512);
        pk.boff[7] = ob;
        k_pack_all<<<ob, 256, 0, stream>>>(pk);
    }

    // ---- classifier + routing (hierarchical compaction, padded counters) ----
    k_h<<<(T_TOTAL / 128) * 4, 256, 0, stream>>>(Xh, Wc1p, bc1, H);
    hipMemsetAsync(ctrs, 0, 1024, stream);
    k_levels<<<T_TOTAL / 64, 256, 0, stream>>>(H, Wc2, bc2, ctrs, idxb, flaglist);
    k_exact<<<128, 256, 0, stream>>>(X, Wc1, bc1, Wc2, bc2, flaglist, ctrs + 96, ctrs, idxb);
    k_offsets<<<1, 64, 0, stream>>>(ctrs, ctrs + 128, HC[0], HC[1], HC[2]);

    // ---- FFN: merged-level launches, chunked only if ws forces it ----
    const int nchunks = FF[2] / CHUNK;
    for (int c = 0; c < nchunks; ++c) {
        int NTc[3];
        for (int l = 0; l < 3; ++l) {
            int rem = FF[l] - c * CHUNK;
            NTc[l] = rem > 0 ? (rem < CHUNK ? rem : CHUNK) / 128 : 0;
        }
        const int g1_0 = 128 * NTc[0], g1_1 = 128 * NTc[1], g1_2 = 128 * NTc[2];
        const int G1 = g1_0 + g1_1 + g1_2;
        const int g2_0 = NTc[0] ? 1024 : 0, g2_1 = NTc[1] ? 1024 : 0, g2_2 = NTc[2] ? 1024 : 0;
        const int G2 = g2_0 + g2_1 + g2_2;
        if (G1 == 0) continue;

        FfnP1 p1;
        p1.Wq0 = W1p[0]; p1.Wq1 = W1p[1]; p1.Wq2 = W1p[2];
        p1.bb0 = b1[0];  p1.bb1 = b1[1];  p1.bb2 = b1[2];
        p1.counts = ctrs; p1.off = ctrs + 128; p1.idx = idxb;
        p1.s0 = g1_0; p1.s01 = g1_0 + g1_1;
        p1.NT0 = NTc[0]; p1.NT1 = NTc[1]; p1.NT2 = NTc[2];
        p1.st0 = HC[0]; p1.st1 = HC[1]; p1.st2 = HC[2];
        p1.no0 = c * CHUNK / 128;
        k_ffn1<<<G1, 256, 0, stream>>>(Xh, Hmid, p1);

        FfnP2 p2;
        p2.Wq0 = W2p[0]; p2.Wq1 = W2p[1]; p2.Wq2 = W2p[2];
        p2.bb0 = b2[0];  p2.bb1 = b2[1];  p2.bb2 = b2[2];
        p2.counts = ctrs; p2.off = ctrs + 128; p2.idx = idxb;
        p2.s2 = g2_2; p2.s21 = g2_2 + g2_1;
        p2.st0 = HC[0]; p2.st1 = HC[1]; p2.st2 = HC[2];
        p2.kb = c * CHUNK / 32;
        p2.kc0 = NTc[0] * 4; p2.kc1 = NTc[1] * 4; p2.kc2 = NTc[2] * 4;
        p2.nf0 = FF[0] / 32; p2.nf1 = FF[1] / 32; p2.nf2 = FF[2] / 32;
        p2.accum = (c > 0) ? 1 : 0;
        k_ffn2<<<G2, 256, 0, stream>>>(Hmid, out, p2);
    }
}

// Round 3
// 569.547 us; speedup vs baseline: 1.3130x; 1.0175x over previous
//
#include <hip/hip_runtime.h>
#include <math.h>

#define T_TOTAL 16384
#define DMODEL  1024
#define MARGIN  2.5e-3f

typedef __attribute__((ext_vector_type(8))) _Float16 f16x8;
typedef __attribute__((ext_vector_type(4))) float    f32x4;

#define SEL3(l, a, b, c) ((l) == 0 ? (a) : (l) == 1 ? (b) : (c))

// counters padded to separate 128B lines: count[l] at ctrs[l*32], flagcnt at
// ctrs[96], offsets at ctrs[128..130].
#define CTR_STRIDE 32

__device__ __forceinline__ float gelu_exact(float x) {
    return 0.5f * x * (1.0f + erff(x * 0.7071067811865476f));
}
__device__ __forceinline__ unsigned short f2h(float f) {
    union { _Float16 h; unsigned short s; } c; c.h = (_Float16)f; return c.s;
}
__device__ __forceinline__ float h2f(unsigned short u) {
    union { unsigned short s; _Float16 h; } c; c.s = u; return (float)c.h;
}
// async global->LDS, 16B per lane; LDS dest = wave-uniform base + lane*16.
__device__ __forceinline__ void gll16(const void* g, void* l) {
    __builtin_amdgcn_global_load_lds(
        (const __attribute__((address_space(1))) unsigned int*)g,
        (__attribute__((address_space(3))) unsigned int*)l, 16, 0, 0);
}

// Panel-chunked XCD swizzle (bijective when gridDim.x % 64 == 0).
__device__ __forceinline__ int swz_bid() {
    const int b = blockIdx.x;
    const int G = gridDim.x;
    if (G & 63) return b;
    const int x = b & 7, j = b >> 3;
    return (x + 8 * (j >> 3)) * 8 + (j & 7);
}

// ---------------------------------------------------------------------------
// k_cvt: Xh = f16(X), whole tensor. 8 floats/thread.
// ---------------------------------------------------------------------------
__global__ __launch_bounds__(256) void k_cvt(
    const float* __restrict__ X, unsigned short* __restrict__ Xh)
{
    const size_t i = ((size_t)blockIdx.x * 256 + threadIdx.x) * 8;
    float4 f0 = *(const float4*)(X + i);
    float4 f1 = *(const float4*)(X + i + 4);
    unsigned short o[8] __attribute__((aligned(16)));
    o[0]=f2h(f0.x); o[1]=f2h(f0.y); o[2]=f2h(f0.z); o[3]=f2h(f0.w);
    o[4]=f2h(f1.x); o[5]=f2h(f1.y); o[6]=f2h(f1.z); o[7]=f2h(f1.w);
    *(uint4*)(Xh + i) = *(uint4*)o;
}

// ---------------------------------------------------------------------------
// k_pack_all: pack all 7 fp32 weights [K][N] into f16 tiles
// [N/128][K/32][128][32] in ONE launch. tile[r][c] = W[kt*32+c][nt*128+r].
// ---------------------------------------------------------------------------
struct PackP {
    const float* src[7];
    unsigned short* dst[7];
    int K[7], N[7];
    int boff[8];
};

__global__ __launch_bounds__(256) void k_pack_all(PackP p)
{
    const int gb = blockIdx.x;
    int t = 0;
    while (t < 6 && gb >= p.boff[t + 1]) ++t;
    const int lb = gb - p.boff[t];
    const float* src = p.src[t];
    unsigned short* dst = p.dst[t];
    const int K = p.K[t], N = p.N[t];

    const int ktiles = K >> 5;
    const int nt = lb / ktiles;
    const int kt = lb % ktiles;
    __shared__ float ls[32][129];
    const int tid = threadIdx.x;
    {
        const int c  = tid >> 3;
        const int n0 = (tid & 7) * 16;
        const float* s = src + (size_t)(kt * 32 + c) * N + (size_t)nt * 128 + n0;
#pragma unroll
        for (int v = 0; v < 4; ++v) {
            float4 f = *(const float4*)(s + v * 4);
            ls[c][n0 + v*4 + 0] = f.x; ls[c][n0 + v*4 + 1] = f.y;
            ls[c][n0 + v*4 + 2] = f.z; ls[c][n0 + v*4 + 3] = f.w;
        }
    }
    __syncthreads();
    {
        const int r  = tid >> 1;
        const int c0 = (tid & 1) * 16;
        unsigned short tmp[16] __attribute__((aligned(16)));
#pragma unroll
        for (int c = 0; c < 16; ++c) tmp[c] = f2h(ls[c0 + c][r]);
        unsigned short* d = dst + (size_t)lb * (128 * 32) + r * 32 + c0;
        *(uint4*)(d)     = *(uint4*)&tmp[0];
        *(uint4*)(d + 8) = *(uint4*)&tmp[8];
    }
}

// ---------------------------------------------------------------------------
// k_h: H = f16( GELU(Xh @ Wc1 + bc1) ), 2-phase prefetch dbuf.
// ---------------------------------------------------------------------------
__global__ __launch_bounds__(256) void k_h(
    const unsigned short* __restrict__ Xh, const unsigned short* __restrict__ Wq,
    const float* __restrict__ bc1, unsigned short* __restrict__ H)
{
    const int bid = swz_bid();
    const int mt = bid >> 2;
    const int nt = bid & 3;
    __shared__ __align__(16) unsigned short As[2 * 128 * 32];
    __shared__ __align__(16) unsigned short Bs[2 * 128 * 32];

    const int tid = threadIdx.x;
    const int w = tid >> 6, ln = tid & 63;
    const int wr = w >> 1, wc = w & 1;
    const int q = ln >> 4, tq = ln & 15;

    f32x4 acc[4][4];
#pragma unroll
    for (int i = 0; i < 4; ++i)
#pragma unroll
        for (int j = 0; j < 4; ++j) acc[i][j] = (f32x4){0.f, 0.f, 0.f, 0.f};

    const int r0 = mt * 128 + w * 32 + (ln >> 2);
    const unsigned short* a0 = Xh + (size_t)r0 * DMODEL + (ln & 3) * 8;
    const unsigned short* a1 = a0 + (size_t)16 * DMODEL;
    const unsigned short* bsr = Wq + (size_t)nt * 32 * 4096 + w * 1024 + ln * 8;

    // prologue: stage tile 0 into buffer 0
    gll16(a0,        As + w * 1024);
    gll16(a1,        As + w * 1024 + 512);
    gll16(bsr,       Bs + w * 1024);
    gll16(bsr + 512, Bs + w * 1024 + 512);
    __syncthreads();

    int cur = 0;
    for (int kt = 0; kt < 32; ++kt) {
        const int nxt = cur ^ 1;
        if (kt + 1 < 32) {
            gll16(a0 + (kt+1) * 32,                    As + nxt * 4096 + w * 1024);
            gll16(a1 + (kt+1) * 32,                    As + nxt * 4096 + w * 1024 + 512);
            gll16(bsr + (size_t)(kt+1) * 4096,         Bs + nxt * 4096 + w * 1024);
            gll16(bsr + (size_t)(kt+1) * 4096 + 512,   Bs + nxt * 4096 + w * 1024 + 512);
        }
        const unsigned short* rA = As + cur * 4096;
        const unsigned short* rB = Bs + cur * 4096;
        f16x8 a[4], b[4];
#pragma unroll
        for (int i = 0; i < 4; ++i) a[i] = *(const f16x8*)(rA + (wr*64 + i*16 + tq) * 32 + q * 8);
#pragma unroll
        for (int j = 0; j < 4; ++j) b[j] = *(const f16x8*)(rB + (wc*64 + j*16 + tq) * 32 + q * 8);
#pragma unroll
        for (int i = 0; i < 4; ++i)
#pragma unroll
            for (int j = 0; j < 4; ++j)
                acc[i][j] = __builtin_amdgcn_mfma_f32_16x16x32_f16(b[j], a[i], acc[i][j], 0, 0, 0);
        __syncthreads();   // drains vmcnt(0): next tile staged; readers done with cur
        cur = nxt;
    }
#pragma unroll
    for (int i = 0; i < 4; ++i) {
        const int t = mt * 128 + wr * 64 + i * 16 + tq;
        unsigned short* hrow = H + (size_t)t * 512;
#pragma unroll
        for (int j = 0; j < 4; ++j) {
            const int cb = nt * 128 + wc * 64 + j * 16 + q * 4;
            float4 bv = *(const float4*)(bc1 + cb);
            f32x4 v = acc[i][j];
            unsigned short o[4] __attribute__((aligned(8)));
            o[0] = f2h(gelu_exact(v[0] + bv.x));
            o[1] = f2h(gelu_exact(v[1] + bv.y));
            o[2] = f2h(gelu_exact(v[2] + bv.z));
            o[3] = f2h(gelu_exact(v[3] + bv.w));
            *(uint2*)(hrow + cb) = *(uint2*)o;
        }
    }
}

// ---------------------------------------------------------------------------
// k_levels: logits = H @ Wc2 + bc2 (fp32), argmax. 64 tokens/block; levels
// staged in LDS; block-level ballot compaction -> ONE atomicAdd per
// (block, level) on 128B-padded counters. Small-margin tokens -> flaglist.
// ---------------------------------------------------------------------------
__global__ __launch_bounds__(256) void k_levels(
    const unsigned short* __restrict__ H, const float* __restrict__ Wc2,
    const float* __restrict__ bc2, int* __restrict__ ctrs,
    int* __restrict__ idxb, int* __restrict__ flaglist)
{
    __shared__ int lvlbuf[64];
    const int tid  = threadIdx.x;
    const int wv   = tid >> 6, lane = tid & 63;
    const int t0   = blockIdx.x * 64;
    const int j0   = lane * 8;

    // hoist this lane's 24 Wc2 coefficients (rows j0..j0+7)
    float wa[8], wb[8], wc[8];
#pragma unroll
    for (int jj = 0; jj < 8; ++jj) {
        const float* wr = Wc2 + (j0 + jj) * 3;
        wa[jj] = wr[0]; wb[jj] = wr[1]; wc[jj] = wr[2];
    }
    const float bz0 = bc2[0], bz1 = bc2[1], bz2 = bc2[2];

    for (int it = 0; it < 16; ++it) {
        const int t = t0 + wv * 16 + it;
        const unsigned short* hrow = H + (size_t)t * 512 + j0;
        unsigned short hu[8] __attribute__((aligned(16)));
        *(uint4*)hu = *(const uint4*)hrow;

        float a0 = 0.f, a1 = 0.f, a2 = 0.f;
#pragma unroll
        for (int jj = 0; jj < 8; ++jj) {
            const float h = h2f(hu[jj]);
            a0 += h * wa[jj]; a1 += h * wb[jj]; a2 += h * wc[jj];
        }
#pragma unroll
        for (int off = 32; off; off >>= 1) {
            a0 += __shfl_xor(a0, off);
            a1 += __shfl_xor(a1, off);
            a2 += __shfl_xor(a2, off);
        }
        if (lane == 0) {
            a0 += bz0; a1 += bz1; a2 += bz2;
            int lvl = 0; float best = a0;
            if (a1 > best) { best = a1; lvl = 1; }
            if (a2 > best) { best = a2; lvl = 2; }
            float second = (lvl == 0) ? fmaxf(a1, a2) : (lvl == 1) ? fmaxf(a0, a2) : fmaxf(a0, a1);
            lvlbuf[wv * 16 + it] = (best - second < MARGIN) ? 3 : lvl;
        }
    }
    __syncthreads();
    // wave 0 compacts all 64 tokens: one atomic per level per block.
    if (tid < 64) {
        const int mylvl = lvlbuf[tid];
        const int mytok = t0 + tid;
#pragma unroll
        for (int lvl = 0; lvl < 4; ++lvl) {
            const unsigned long long m = __ballot(mylvl == lvl);
            int base = 0;
            if (tid == 0) {
                const int cnt = __popcll(m);
                if (cnt) base = atomicAdd(&ctrs[lvl * CTR_STRIDE], cnt);
            }
            base = __shfl(base, 0);
            if (mylvl == lvl) {
                const int pos = base + __popcll(m & ((1ull << tid) - 1ull));
                if (lvl < 3) idxb[lvl * T_TOTAL + pos] = mytok;
                else         flaglist[pos] = mytok;
            }
        }
    }
}

// ---------------------------------------------------------------------------
// k_exact: exact fp32 classifier for flagged tokens (8/block, grid-stride);
// appends its tokens to idxb directly (nflag is tiny -> low contention).
// ---------------------------------------------------------------------------
__global__ __launch_bounds__(256) void k_exact(
    const float* __restrict__ X, const float* __restrict__ Wc1,
    const float* __restrict__ bc1, const float* __restrict__ Wc2,
    const float* __restrict__ bc2, const int* __restrict__ flaglist,
    const int* __restrict__ flagcnt, int* __restrict__ ctrs,
    int* __restrict__ idxb)
{
    __shared__ float xs[1024][8];
    __shared__ float red[4][8][3];
    const int tid = threadIdx.x;
    const int nflag = flagcnt[0];

    for (int g = blockIdx.x; g * 8 < nflag; g += gridDim.x) {
        {
            const int s   = tid >> 5;
            const int l32 = tid & 31;
            int fi = g * 8 + s; if (fi >= nflag) fi = nflag - 1;
            const float* xr = X + (size_t)flaglist[fi] * DMODEL;
#pragma unroll
            for (int kk = 0; kk < 32; ++kk) {
                const int k = kk * 32 + l32;
                xs[k][s] = xr[k];
            }
        }
        __syncthreads();
        const int j = tid;
        float acc0[8], acc1[8];
#pragma unroll
        for (int s = 0; s < 8; ++s) { acc0[s] = 0.f; acc1[s] = 0.f; }
        for (int k = 0; k < 1024; ++k) {
            float4 xa = *(const float4*)&xs[k][0];
            float4 xb = *(const float4*)&xs[k][4];
            const float w0 = Wc1[(size_t)k * 512 + j];
            const float w1 = Wc1[(size_t)k * 512 + j + 256];
            acc0[0] += xa.x * w0; acc0[1] += xa.y * w0; acc0[2] += xa.z * w0; acc0[3] += xa.w * w0;
            acc0[4] += xb.x * w0; acc0[5] += xb.y * w0; acc0[6] += xb.z * w0; acc0[7] += xb.w * w0;
            acc1[0] += xa.x * w1; acc1[1] += xa.y * w1; acc1[2] += xa.z * w1; acc1[3] += xa.w * w1;
            acc1[4] += xb.x * w1; acc1[5] += xb.y * w1; acc1[6] += xb.z * w1; acc1[7] += xb.w * w1;
        }
        float p[8][3];
        {
            const float b0 = bc1[j], b1 = bc1[j + 256];
            const float* w2a = Wc2 + j * 3;
            const float* w2b = Wc2 + (j + 256) * 3;
#pragma unroll
            for (int s = 0; s < 8; ++s) {
                const float h0 = gelu_exact(acc0[s] + b0);
                const float h1 = gelu_exact(acc1[s] + b1);
                p[s][0] = h0 * w2a[0] + h1 * w2b[0];
                p[s][1] = h0 * w2a[1] + h1 * w2b[1];
                p[s][2] = h0 * w2a[2] + h1 * w2b[2];
            }
        }
#pragma unroll
        for (int off = 32; off; off >>= 1)
#pragma unroll
            for (int s = 0; s < 8; ++s) {
                p[s][0] += __shfl_xor(p[s][0], off);
                p[s][1] += __shfl_xor(p[s][1], off);
                p[s][2] += __shfl_xor(p[s][2], off);
            }
        if ((tid & 63) == 0) {
            const int w = tid >> 6;
#pragma unroll
            for (int s = 0; s < 8; ++s) {
                red[w][s][0] = p[s][0]; red[w][s][1] = p[s][1]; red[w][s][2] = p[s][2];
            }
        }
        __syncthreads();
        if (tid < 8) {
            const int fi = g * 8 + tid;
            if (fi < nflag) {
                float l0 = bc2[0], l1 = bc2[1], l2 = bc2[2];
#pragma unroll
                for (int w = 0; w < 4; ++w) {
                    l0 += red[w][tid][0]; l1 += red[w][tid][1]; l2 += red[w][tid][2];
                }
                int lvl = 0; float best = l0;
                if (l1 > best) { best = l1; lvl = 1; }
                if (l2 > best) { best = l2; lvl = 2; }
                const int tok = flaglist[fi];
                const int pos = atomicAdd(&ctrs[lvl * CTR_STRIDE], 1);
                idxb[lvl * T_TOTAL + pos] = tok;
            }
        }
        __syncthreads();
    }
}

// ---------------------------------------------------------------------------
__global__ void k_offsets(const int* __restrict__ ctrs, int* __restrict__ off,
                          int h0, int h1, int h2)
{
    if (threadIdx.x == 0 && blockIdx.x == 0) {
        off[0] = 0;
        off[1] = ctrs[0] * h0;
        off[2] = ctrs[0] * h0 + ctrs[CTR_STRIDE] * h1;
    }
}

// ---------------------------------------------------------------------------
// k_ffn1: Hmid = f16(GELU(Xh_gathered @ W1 + b1)), merged levels,
// 2-phase prefetch dbuf.
// ---------------------------------------------------------------------------
struct FfnP1 {
    const unsigned short *Wq0, *Wq1, *Wq2;
    const float *bb0, *bb1, *bb2;
    const int* counts; const int* off; const int* idx;
    int s0, s01;
    int NT0, NT1, NT2;
    int st0, st1, st2;
    int no0;
};

__global__ __launch_bounds__(256) void k_ffn1(
    const unsigned short* __restrict__ Xh, unsigned short* __restrict__ Hmid, FfnP1 p)
{
    const int bid = swz_bid();
    int l, r;
    if (bid < p.s0)       { l = 0; r = bid; }
    else if (bid < p.s01) { l = 1; r = bid - p.s0; }
    else                  { l = 2; r = bid - p.s01; }
    const int NT = SEL3(l, p.NT0, p.NT1, p.NT2);
    const int mt = r / NT, nt = r % NT;
    const int n  = p.counts[l * CTR_STRIDE];
    if (mt * 128 >= n) return;

    const int* idx = p.idx + l * T_TOTAL;
    const unsigned short* Wq = SEL3(l, p.Wq0, p.Wq1, p.Wq2);
    const float* bb = SEL3(l, p.bb0, p.bb1, p.bb2);
    const int stride = SEL3(l, p.st0, p.st1, p.st2);
    const size_t hoff = (size_t)p.off[l];

    __shared__ __align__(16) unsigned short As[2 * 128 * 32];
    __shared__ __align__(16) unsigned short Bs[2 * 128 * 32];

    const int tid = threadIdx.x;
    const int w = tid >> 6, ln = tid & 63;
    const int wr = w >> 1, wc = w & 1;
    const int q = ln >> 4, tq = ln & 15;

    f32x4 acc[4][4];
#pragma unroll
    for (int i = 0; i < 4; ++i)
#pragma unroll
        for (int j = 0; j < 4; ++j) acc[i][j] = (f32x4){0.f, 0.f, 0.f, 0.f};

    int r0 = mt * 128 + w * 32 + (ln >> 2);
    int r1 = r0 + 16;
    if (r0 >= n) r0 = n - 1;
    if (r1 >= n) r1 = n - 1;
    const unsigned short* a0 = Xh + (size_t)idx[r0] * DMODEL + (ln & 3) * 8;
    const unsigned short* a1 = Xh + (size_t)idx[r1] * DMODEL + (ln & 3) * 8;
    const unsigned short* bsr = Wq + (size_t)(p.no0 + nt) * 32 * 4096 + w * 1024 + ln * 8;

    gll16(a0,        As + w * 1024);
    gll16(a1,        As + w * 1024 + 512);
    gll16(bsr,       Bs + w * 1024);
    gll16(bsr + 512, Bs + w * 1024 + 512);
    __syncthreads();

    int cur = 0;
    for (int kt = 0; kt < 32; ++kt) {
        const int nxt = cur ^ 1;
        if (kt + 1 < 32) {
            gll16(a0 + (kt+1) * 32,                  As + nxt * 4096 + w * 1024);
            gll16(a1 + (kt+1) * 32,                  As + nxt * 4096 + w * 1024 + 512);
            gll16(bsr + (size_t)(kt+1) * 4096,       Bs + nxt * 4096 + w * 1024);
            gll16(bsr + (size_t)(kt+1) * 4096 + 512, Bs + nxt * 4096 + w * 1024 + 512);
        }
        const unsigned short* rA = As + cur * 4096;
        const unsigned short* rB = Bs + cur * 4096;
        f16x8 a[4], b[4];
#pragma unroll
        for (int i = 0; i < 4; ++i) a[i] = *(const f16x8*)(rA + (wr*64 + i*16 + tq) * 32 + q * 8);
#pragma unroll
        for (int j = 0; j < 4; ++j) b[j] = *(const f16x8*)(rB + (wc*64 + j*16 + tq) * 32 + q * 8);
#pragma unroll
        for (int i = 0; i < 4; ++i)
#pragma unroll
            for (int j = 0; j < 4; ++j)
                acc[i][j] = __builtin_amdgcn_mfma_f32_16x16x32_f16(b[j], a[i], acc[i][j], 0, 0, 0);
        __syncthreads();
        cur = nxt;
    }
#pragma unroll
    for (int i = 0; i < 4; ++i) {
        const int pp = mt * 128 + wr * 64 + i * 16 + tq;
        if (pp < n) {
            unsigned short* hrow = Hmid + hoff + (size_t)pp * stride;
#pragma unroll
            for (int j = 0; j < 4; ++j) {
                const int cb = nt * 128 + wc * 64 + j * 16 + q * 4;
                float4 bv = *(const float4*)(bb + p.no0 * 128 + cb);
                f32x4 v = acc[i][j];
                unsigned short o[4] __attribute__((aligned(8)));
                o[0] = f2h(gelu_exact(v[0] + bv.x));
                o[1] = f2h(gelu_exact(v[1] + bv.y));
                o[2] = f2h(gelu_exact(v[2] + bv.z));
                o[3] = f2h(gelu_exact(v[3] + bv.w));
                *(uint2*)(hrow + cb) = *(uint2*)o;
            }
        }
    }
}

// ---------------------------------------------------------------------------
// k_ffn2: out = Hmid @ W2 + b2 (scatter), merged levels, 2-phase prefetch
// dbuf. Work ordering: level 2 (K=4096) first, then 1, then 0.
// ---------------------------------------------------------------------------
struct FfnP2 {
    const unsigned short *Wq0, *Wq1, *Wq2;
    const float *bb0, *bb1, *bb2;
    const int* counts; const int* off; const int* idx;
    int s2, s21;              // [0,s2)=level2, [s2,s21)=level1, [s21,..)=level0
    int st0, st1, st2;
    int kb;
    int kc0, kc1, kc2;
    int nf0, nf1, nf2;
    int accum;
};

__global__ __launch_bounds__(256) void k_ffn2(
    const unsigned short* __restrict__ Hmid, float* __restrict__ out, FfnP2 p)
{
    const int bid = swz_bid();
    int l, r;
    if (bid < p.s2)       { l = 2; r = bid; }
    else if (bid < p.s21) { l = 1; r = bid - p.s2; }
    else                  { l = 0; r = bid - p.s21; }
    const int mt = r >> 3, nt = r & 7;
    const int n  = p.counts[l * CTR_STRIDE];
    if (mt * 128 >= n) return;

    const int* idx = p.idx + l * T_TOTAL;
    const unsigned short* Wq = SEL3(l, p.Wq0, p.Wq1, p.Wq2);
    const float* bb = SEL3(l, p.bb0, p.bb1, p.bb2);
    const int stride = SEL3(l, p.st0, p.st1, p.st2);
    const int KC = SEL3(l, p.kc0, p.kc1, p.kc2);
    const int nf = SEL3(l, p.nf0, p.nf1, p.nf2);
    const size_t hoff = (size_t)p.off[l];

    __shared__ __align__(16) unsigned short As[2 * 128 * 32];
    __shared__ __align__(16) unsigned short Bs[2 * 128 * 32];

    const int tid = threadIdx.x;
    const int w = tid >> 6, ln = tid & 63;
    const int wr = w >> 1, wc = w & 1;
    const int q = ln >> 4, tq = ln & 15;

    f32x4 acc[4][4];
#pragma unroll
    for (int i = 0; i < 4; ++i)
#pragma unroll
        for (int j = 0; j < 4; ++j) acc[i][j] = (f32x4){0.f, 0.f, 0.f, 0.f};

    int r0 = mt * 128 + w * 32 + (ln >> 2);
    int r1 = r0 + 16;
    if (r0 >= n) r0 = n - 1;
    if (r1 >= n) r1 = n - 1;
    const unsigned short* a0 = Hmid + hoff + (size_t)r0 * stride + (ln & 3) * 8;
    const unsigned short* a1 = Hmid + hoff + (size_t)r1 * stride + (ln & 3) * 8;
    const unsigned short* bsr = Wq + ((size_t)nt * nf + p.kb) * 4096 + w * 1024 + ln * 8;

    gll16(a0,        As + w * 1024);
    gll16(a1,        As + w * 1024 + 512);
    gll16(bsr,       Bs + w * 1024);
    gll16(bsr + 512, Bs + w * 1024 + 512);
    __syncthreads();

    int cur = 0;
    for (int kt = 0; kt < KC; ++kt) {
        const int nxt = cur ^ 1;
        if (kt + 1 < KC) {
            gll16(a0 + (kt+1) * 32,                  As + nxt * 4096 + w * 1024);
            gll16(a1 + (kt+1) * 32,                  As + nxt * 4096 + w * 1024 + 512);
            gll16(bsr + (size_t)(kt+1) * 4096,       Bs + nxt * 4096 + w * 1024);
            gll16(bsr + (size_t)(kt+1) * 4096 + 512, Bs + nxt * 4096 + w * 1024 + 512);
        }
        const unsigned short* rA = As + cur * 4096;
        const unsigned short* rB = Bs + cur * 4096;
        f16x8 a[4], b[4];
#pragma unroll
        for (int i = 0; i < 4; ++i) a[i] = *(const f16x8*)(rA + (wr*64 + i*16 + tq) * 32 + q * 8);
#pragma unroll
        for (int j = 0; j < 4; ++j) b[j] = *(const f16x8*)(rB + (wc*64 + j*16 + tq) * 32 + q * 8);
#pragma unroll
        for (int i = 0; i < 4; ++i)
#pragma unroll
            for (int j = 0; j < 4; ++j)
                acc[i][j] = __builtin_amdgcn_mfma_f32_16x16x32_f16(b[j], a[i], acc[i][j], 0, 0, 0);
        __syncthreads();
        cur = nxt;
    }
#pragma unroll
    for (int i = 0; i < 4; ++i) {
        const int pp = mt * 128 + wr * 64 + i * 16 + tq;
        if (pp < n) {
            float* orow = out + (size_t)idx[pp] * DMODEL;
#pragma unroll
            for (int j = 0; j < 4; ++j) {
                const int cb = nt * 128 + wc * 64 + j * 16 + q * 4;
                f32x4 v = acc[i][j];
                float4 res;
                if (p.accum) {
                    float4 cur4 = *(const float4*)(orow + cb);
                    res.x = cur4.x + v[0]; res.y = cur4.y + v[1];
                    res.z = cur4.z + v[2]; res.w = cur4.w + v[3];
                } else {
                    float4 bv = *(const float4*)(bb + cb);
                    res.x = v[0] + bv.x; res.y = v[1] + bv.y;
                    res.z = v[2] + bv.z; res.w = v[3] + bv.w;
                }
                *(float4*)(orow + cb) = res;
            }
        }
    }
}

// ---------------------------------------------------------------------------
extern "C" void kernel_launch(void* const* d_in, const int* in_sizes, int n_in,
                              void* d_out, int out_size, void* d_ws, size_t ws_size,
                              hipStream_t stream)
{
    (void)in_sizes; (void)n_in; (void)out_size;

    const float* X   = (const float*)d_in[0];
    const float* Wc1 = (const float*)d_in[1];
    const float* bc1 = (const float*)d_in[2];
    const float* Wc2 = (const float*)d_in[3];
    const float* bc2 = (const float*)d_in[4];
    const float* W1[3] = {(const float*)d_in[5],  (const float*)d_in[9],  (const float*)d_in[13]};
    const float* b1[3] = {(const float*)d_in[6],  (const float*)d_in[10], (const float*)d_in[14]};
    const float* W2[3] = {(const float*)d_in[7],  (const float*)d_in[11], (const float*)d_in[15]};
    const float* b2[3] = {(const float*)d_in[8],  (const float*)d_in[12], (const float*)d_in[16]};
    float* out = (float*)d_out;
    const int FF[3] = {1024, 2048, 4096};

    // ---- workspace layout (Hmid last, sized to what remains) ----
    char* w = (char*)d_ws;
    size_t o = 0;
    auto take = [&](size_t bytes) -> char* {
        char* p = w + o;
        o = (o + bytes + 255) & ~(size_t)255;
        return p;
    };
    unsigned short* W1p[3]; for (int l = 0; l < 3; ++l) W1p[l] = (unsigned short*)take((size_t)1024 * FF[l] * 2);
    unsigned short* W2p[3]; for (int l = 0; l < 3; ++l) W2p[l] = (unsigned short*)take((size_t)1024 * FF[l] * 2);
    unsigned short* Wc1p = (unsigned short*)take((size_t)1024 * 512 * 2);
    unsigned short* Xh   = (unsigned short*)take((size_t)T_TOTAL * DMODEL * 2);
    unsigned short* H    = (unsigned short*)take((size_t)T_TOTAL * 512 * 2);
    int* flaglist = (int*)take((size_t)T_TOTAL * 4);
    int* idxb     = (int*)take((size_t)3 * T_TOTAL * 4);
    int* ctrs     = (int*)take(1024);  // count[l]@l*32, flagcnt@96, off@128..130
    unsigned short* Hmid = (unsigned short*)(w + o);
    const size_t avail = ws_size > o ? ws_size - o : 0;

    int CHUNK = 256;
    const int cand[4] = {4096, 2048, 1024, 512};
    for (int ci = 0; ci < 4; ++ci)
        if ((size_t)T_TOTAL * cand[ci] * 2 <= avail) { CHUNK = cand[ci]; break; }
    int HC[3]; for (int l = 0; l < 3; ++l) HC[l] = FF[l] < CHUNK ? FF[l] : CHUNK;

    // ---- convert + pack (all 7 packs in one launch) ----
    k_cvt<<<(T_TOTAL * DMODEL) / (256 * 8), 256, 0, stream>>>(X, Xh);
    {
        PackP pk;
        int ob = 0, slot = 0;
        auto addpk = [&](const float* s, unsigned short* d2, int K, int N) {
            pk.src[slot] = s; pk.dst[slot] = d2; pk.K[slot] = K; pk.N[slot] = N;
            pk.boff[slot] = ob; ob += (N / 128) * (K / 32); ++slot;
        };
        for (int l = 0; l < 3; ++l) addpk(W1[l], W1p[l], 1024, FF[l]);
        for (int l = 0; l < 3; ++l) addpk(W2[l], W2p[l], FF[l], 1024);
        addpk(Wc1, Wc1p, 1024, 512);
        pk.boff[7] = ob;
        k_pack_all<<<ob, 256, 0, stream>>>(pk);
    }

    // ---- classifier + routing (hierarchical compaction, padded counters) ----
    k_h<<<(T_TOTAL / 128) * 4, 256, 0, stream>>>(Xh, Wc1p, bc1, H);
    hipMemsetAsync(ctrs, 0, 1024, stream);
    k_levels<<<T_TOTAL / 64, 256, 0, stream>>>(H, Wc2, bc2, ctrs, idxb, flaglist);
    k_exact<<<128, 256, 0, stream>>>(X, Wc1, bc1, Wc2, bc2, flaglist, ctrs + 96, ctrs, idxb);
    k_offsets<<<1, 64, 0, stream>>>(ctrs, ctrs + 128, HC[0], HC[1], HC[2]);

    // ---- FFN: merged-level launches, chunked only if ws forces it ----
    const int nchunks = FF[2] / CHUNK;
    for (int c = 0; c < nchunks; ++c) {
        int NTc[3];
        for (int l = 0; l < 3; ++l) {
            int rem = FF[l] - c * CHUNK;
            NTc[l] = rem > 0 ? (rem < CHUNK ? rem : CHUNK) / 128 : 0;
        }
        const int g1_0 = 128 * NTc[0], g1_1 = 128 * NTc[1], g1_2 = 128 * NTc[2];
        const int G1 = g1_0 + g1_1 + g1_2;
        const int g2_0 = NTc[0] ? 1024 : 0, g2_1 = NTc[1] ? 1024 : 0, g2_2 = NTc[2] ? 1024 : 0;
        const int G2 = g2_0 + g2_1 + g2_2;
        if (G1 == 0) continue;

        FfnP1 p1;
        p1.Wq0 = W1p[0]; p1.Wq1 = W1p[1]; p1.Wq2 = W1p[2];
        p1.bb0 = b1[0];  p1.bb1 = b1[1];  p1.bb2 = b1[2];
        p1.counts = ctrs; p1.off = ctrs + 128; p1.idx = idxb;
        p1.s0 = g1_0; p1.s01 = g1_0 + g1_1;
        p1.NT0 = NTc[0]; p1.NT1 = NTc[1]; p1.NT2 = NTc[2];
        p1.st0 = HC[0]; p1.st1 = HC[1]; p1.st2 = HC[2];
        p1.no0 = c * CHUNK / 128;
        k_ffn1<<<G1, 256, 0, stream>>>(Xh, Hmid, p1);

        FfnP2 p2;
        p2.Wq0 = W2p[0]; p2.Wq1 = W2p[1]; p2.Wq2 = W2p[2];
        p2.bb0 = b2[0];  p2.bb1 = b2[1];  p2.bb2 = b2[2];
        p2.counts = ctrs; p2.off = ctrs + 128; p2.idx = idxb;
        p2.s2 = g2_2; p2.s21 = g2_2 + g2_1;
        p2.st0 = HC[0]; p2.st1 = HC[1]; p2.st2 = HC[2];
        p2.kb = c * CHUNK / 32;
        p2.kc0 = NTc[0] * 4; p2.kc1 = NTc[1] * 4; p2.kc2 = NTc[2] * 4;
        p2.nf0 = FF[0] / 32; p2.nf1 = FF[1] / 32; p2.nf2 = FF[2] / 32;
        p2.accum = (c > 0) ? 1 : 0;
        k_ffn2<<<G2, 256, 0, stream>>>(Hmid, out, p2);
    }
}